// Round 1
// baseline (3153.214 us; speedup 1.0000x reference)
//
#include <hip/hip_runtime.h>

#define B_   32
#define N_   64
#define NH   16
#define R_   1024
#define REP  1024
#define REP2 512
#define M_   1008           // 16*63
#define BM   (B_ * M_)      // 32256
#define NCLS 117

// ---------------------------------------------------------------------------
// Generic 128x128 fp32 GEMM:  C[M,N] = opt_relu(A[M,K] @ W[K,N] + bias)
// grid: (N/128, M/128), block 256.  M,N % 128 == 0, K % 16 == 0.
// ---------------------------------------------------------------------------
__global__ __launch_bounds__(256)
void gemm128(const float* __restrict__ A, const float* __restrict__ W,
             const float* __restrict__ bias, float* __restrict__ C,
             int K, int Nc, int doRelu)
{
    __shared__ float As[16][132];
    __shared__ float Bs[16][132];
    const int tid = threadIdx.x;
    const int tx = tid & 15, ty = tid >> 4;
    const int row0 = blockIdx.y * 128;
    const int col0 = blockIdx.x * 128;

    const int ar  = tid >> 2;           // 0..63, handles rows ar and ar+64
    const int akq = (tid & 3) << 2;     // 0,4,8,12
    const float* Ap0 = A + (size_t)(row0 + ar) * K + akq;
    const float* Ap1 = A + (size_t)(row0 + ar + 64) * K + akq;

    const int bk  = tid >> 5;           // 0..7, handles k rows bk and bk+8
    const int bcq = (tid & 31) << 2;    // 0..124
    const float* Bp0 = W + (size_t)bk * Nc + col0 + bcq;
    const float* Bp1 = W + (size_t)(bk + 8) * Nc + col0 + bcq;

    float acc[2][2][4][4] = {};

    for (int k0 = 0; k0 < K; k0 += 16) {
        float4 a0 = *(const float4*)(Ap0 + k0);
        float4 a1 = *(const float4*)(Ap1 + k0);
        float4 b0 = *(const float4*)(Bp0 + (size_t)k0 * Nc);
        float4 b1 = *(const float4*)(Bp1 + (size_t)k0 * Nc);
        __syncthreads();
        As[akq + 0][ar] = a0.x; As[akq + 1][ar] = a0.y;
        As[akq + 2][ar] = a0.z; As[akq + 3][ar] = a0.w;
        As[akq + 0][ar + 64] = a1.x; As[akq + 1][ar + 64] = a1.y;
        As[akq + 2][ar + 64] = a1.z; As[akq + 3][ar + 64] = a1.w;
        *(float4*)&Bs[bk][bcq]     = b0;
        *(float4*)&Bs[bk + 8][bcq] = b1;
        __syncthreads();
#pragma unroll
        for (int k = 0; k < 16; ++k) {
            float a[8], b[8];
            *(float4*)&a[0] = *(const float4*)&As[k][ty * 4];
            *(float4*)&a[4] = *(const float4*)&As[k][64 + ty * 4];
            *(float4*)&b[0] = *(const float4*)&Bs[k][tx * 4];
            *(float4*)&b[4] = *(const float4*)&Bs[k][64 + tx * 4];
#pragma unroll
            for (int ih = 0; ih < 2; ++ih)
#pragma unroll
            for (int i = 0; i < 4; ++i)
#pragma unroll
            for (int jh = 0; jh < 2; ++jh)
#pragma unroll
            for (int j = 0; j < 4; ++j)
                acc[ih][jh][i][j] = fmaf(a[ih * 4 + i], b[jh * 4 + j], acc[ih][jh][i][j]);
        }
    }

#pragma unroll
    for (int ih = 0; ih < 2; ++ih)
#pragma unroll
    for (int i = 0; i < 4; ++i) {
        int r = row0 + ih * 64 + ty * 4 + i;
#pragma unroll
        for (int jh = 0; jh < 2; ++jh) {
            int c = col0 + jh * 64 + tx * 4;
            float4 o;
            o.x = acc[ih][jh][i][0]; o.y = acc[ih][jh][i][1];
            o.z = acc[ih][jh][i][2]; o.w = acc[ih][jh][i][3];
            if (bias) {
                float4 bv = *(const float4*)(bias + c);
                o.x += bv.x; o.y += bv.y; o.z += bv.z; o.w += bv.w;
            }
            if (doRelu) {
                o.x = fmaxf(o.x, 0.f); o.y = fmaxf(o.y, 0.f);
                o.z = fmaxf(o.z, 0.f); o.w = fmaxf(o.w, 0.f);
            }
            *(float4*)(C + (size_t)r * Nc + c) = o;
        }
    }
}

// ---------------------------------------------------------------------------
// Big pair GEMM (fused):  rows = (b,m) pairs; A[row,k] = relu(U[b,x,k]+V[b,y,k])
// computes h2 = relu(A@W2 + b2) and immediately the partial dot h2 . W3 over
// this block's 128-col chunk -> wpart[chunk][row].  grid (4, 252), block 256.
// ---------------------------------------------------------------------------
__global__ __launch_bounds__(256)
void pair_gemm(const float* __restrict__ U, const float* __restrict__ V,
               const float* __restrict__ W2, const float* __restrict__ b2,
               const float* __restrict__ W3f, float* __restrict__ wpart)
{
    __shared__ float As[16][132];
    __shared__ float Bs[16][132];
    __shared__ float red[128][17];
    const int tid = threadIdx.x;
    const int tx = tid & 15, ty = tid >> 4;
    const int row0 = blockIdx.y * 128;   // over 32256
    const int col0 = blockIdx.x * 128;   // over 512

    const int ar  = tid >> 2;
    const int akq = (tid & 3) << 2;
    const float* Up[2];
    const float* Vp[2];
#pragma unroll
    for (int h = 0; h < 2; ++h) {
        int rg = row0 + ar + h * 64;
        int b = rg / M_;
        int m = rg % M_;
        int x = m / 63;
        int j = m % 63;
        int y = j + (j >= x ? 1 : 0);
        Up[h] = U + ((size_t)b * NH + x) * REP + akq;
        Vp[h] = V + ((size_t)b * N_ + y) * REP + akq;
    }
    const int bk  = tid >> 5;
    const int bcq = (tid & 31) << 2;
    const float* Bp0 = W2 + (size_t)bk * REP2 + col0 + bcq;
    const float* Bp1 = W2 + (size_t)(bk + 8) * REP2 + col0 + bcq;

    float acc[2][2][4][4] = {};

    for (int k0 = 0; k0 < REP; k0 += 16) {
        float4 u0 = *(const float4*)(Up[0] + k0);
        float4 v0 = *(const float4*)(Vp[0] + k0);
        float4 u1 = *(const float4*)(Up[1] + k0);
        float4 v1 = *(const float4*)(Vp[1] + k0);
        float4 b0 = *(const float4*)(Bp0 + (size_t)k0 * REP2);
        float4 b1 = *(const float4*)(Bp1 + (size_t)k0 * REP2);
        float4 h0, h1;
        h0.x = fmaxf(u0.x + v0.x, 0.f); h0.y = fmaxf(u0.y + v0.y, 0.f);
        h0.z = fmaxf(u0.z + v0.z, 0.f); h0.w = fmaxf(u0.w + v0.w, 0.f);
        h1.x = fmaxf(u1.x + v1.x, 0.f); h1.y = fmaxf(u1.y + v1.y, 0.f);
        h1.z = fmaxf(u1.z + v1.z, 0.f); h1.w = fmaxf(u1.w + v1.w, 0.f);
        __syncthreads();
        As[akq + 0][ar] = h0.x; As[akq + 1][ar] = h0.y;
        As[akq + 2][ar] = h0.z; As[akq + 3][ar] = h0.w;
        As[akq + 0][ar + 64] = h1.x; As[akq + 1][ar + 64] = h1.y;
        As[akq + 2][ar + 64] = h1.z; As[akq + 3][ar + 64] = h1.w;
        *(float4*)&Bs[bk][bcq]     = b0;
        *(float4*)&Bs[bk + 8][bcq] = b1;
        __syncthreads();
#pragma unroll
        for (int k = 0; k < 16; ++k) {
            float a[8], b[8];
            *(float4*)&a[0] = *(const float4*)&As[k][ty * 4];
            *(float4*)&a[4] = *(const float4*)&As[k][64 + ty * 4];
            *(float4*)&b[0] = *(const float4*)&Bs[k][tx * 4];
            *(float4*)&b[4] = *(const float4*)&Bs[k][64 + tx * 4];
#pragma unroll
            for (int ih = 0; ih < 2; ++ih)
#pragma unroll
            for (int i = 0; i < 4; ++i)
#pragma unroll
            for (int jh = 0; jh < 2; ++jh)
#pragma unroll
            for (int j = 0; j < 4; ++j)
                acc[ih][jh][i][j] = fmaf(a[ih * 4 + i], b[jh * 4 + j], acc[ih][jh][i][j]);
        }
    }

    // epilogue: h2 = relu(acc + b2), partial dot with W3 over this col chunk
    float4 b2v[2], w3v[2];
    b2v[0] = *(const float4*)(b2 + col0 + tx * 4);
    b2v[1] = *(const float4*)(b2 + col0 + 64 + tx * 4);
    w3v[0] = *(const float4*)(W3f + col0 + tx * 4);
    w3v[1] = *(const float4*)(W3f + col0 + 64 + tx * 4);
#pragma unroll
    for (int ih = 0; ih < 2; ++ih)
#pragma unroll
    for (int i = 0; i < 4; ++i) {
        float part = 0.f;
#pragma unroll
        for (int jh = 0; jh < 2; ++jh) {
            float h;
            h = fmaxf(acc[ih][jh][i][0] + ((jh == 0) ? b2v[0].x : b2v[1].x), 0.f);
            part += h * ((jh == 0) ? w3v[0].x : w3v[1].x);
            h = fmaxf(acc[ih][jh][i][1] + ((jh == 0) ? b2v[0].y : b2v[1].y), 0.f);
            part += h * ((jh == 0) ? w3v[0].y : w3v[1].y);
            h = fmaxf(acc[ih][jh][i][2] + ((jh == 0) ? b2v[0].z : b2v[1].z), 0.f);
            part += h * ((jh == 0) ? w3v[0].z : w3v[1].z);
            h = fmaxf(acc[ih][jh][i][3] + ((jh == 0) ? b2v[0].w : b2v[1].w), 0.f);
            part += h * ((jh == 0) ? w3v[0].w : w3v[1].w);
        }
        red[ih * 64 + ty * 4 + i][tx] = part;
    }
    __syncthreads();
    if (tid < 128) {
        float s = 0.f;
#pragma unroll
        for (int t = 0; t < 16; ++t) s += red[tid][t];
        wpart[blockIdx.x * BM + row0 + tid] = s;
    }
}

// ---------------------------------------------------------------------------
__global__ void zero_aw(float* __restrict__ Aw)
{
    int i = blockIdx.x * 256 + threadIdx.x;
    if (i < B_ * NH * N_) Aw[i] = 0.f;
}

__global__ void reduce_w(const float* __restrict__ wpart, const float* __restrict__ b3,
                         float* __restrict__ Aw)
{
    int r = blockIdx.x * 256 + threadIdx.x;
    if (r >= BM) return;
    float s = b3[0];
#pragma unroll
    for (int c = 0; c < 4; ++c) s += wpart[c * BM + r];
    float sig = 1.f / (1.f + expf(-s));
    int b = r / M_, m = r % M_;
    int x = m / 63, j = m % 63;
    int y = j + (j >= x ? 1 : 0);
    Aw[(b * NH + x) * N_ + y] = sig;
}

// msg_h[b] = A[b] @ Go[b]   ([16,64]@[64,1024]);  grid (32, 8), block 128
__global__ __launch_bounds__(128)
void msgh_kernel(const float* __restrict__ Aw, const float* __restrict__ Go,
                 float* __restrict__ msgh)
{
    __shared__ float Al[NH * N_];
    __shared__ float Gl[N_][128];
    int b = blockIdx.x, c0 = blockIdx.y * 128, t = threadIdx.x;
    for (int i = t; i < NH * N_; i += 128) Al[i] = Aw[b * NH * N_ + i];
    for (int y = 0; y < N_; ++y) Gl[y][t] = Go[((size_t)(b * N_ + y)) * REP + c0 + t];
    __syncthreads();
    for (int x = 0; x < NH; ++x) {
        float s = 0.f;
#pragma unroll 8
        for (int y = 0; y < N_; ++y) s += Al[x * N_ + y] * Gl[y][t];
        msgh[((size_t)(b * NH + x)) * REP + c0 + t] = s;
    }
}

// msg_o[b] = A[b]^T @ Gs[b]  ([64,16]@[16,1024]);  grid (32, 8), block 128
__global__ __launch_bounds__(128)
void msgo_kernel(const float* __restrict__ Aw, const float* __restrict__ Gs,
                 float* __restrict__ msgo)
{
    __shared__ float Al[NH * N_];
    __shared__ float Gl[NH][128];
    int b = blockIdx.x, c0 = blockIdx.y * 128, t = threadIdx.x;
    for (int i = t; i < NH * N_; i += 128) Al[i] = Aw[b * NH * N_ + i];
    for (int x = 0; x < NH; ++x) Gl[x][t] = Gs[((size_t)(b * NH + x)) * REP + c0 + t];
    __syncthreads();
    for (int y = 0; y < N_; ++y) {
        float s = 0.f;
#pragma unroll
        for (int x = 0; x < NH; ++x) s += Al[x * N_ + y] * Gl[x][t];
        msgo[((size_t)(b * N_ + y)) * REP + c0 + t] = s;
    }
}

// ---------------------------------------------------------------------------
__global__ void copy_f4(const float4* __restrict__ src, float4* __restrict__ dst, int n4)
{
    int i = blockIdx.x * 256 + threadIdx.x;
    if (i < n4) dst[i] = src[i];
}

// gather humans: Hg[b*16+x] = enc[b*64+x]
__global__ void build_hg(const float* __restrict__ enc, float* __restrict__ Hg)
{
    int i = blockIdx.x * 256 + threadIdx.x;     // over 512*256 float4
    if (i >= 512 * 256) return;
    int r = i >> 8, q = i & 255;
    int b = r >> 4, x = r & 15;
    ((float4*)Hg)[i] = ((const float4*)enc)[(b * 64 + x) * 256 + q];
}

// Cc1[b*16+x] = concat(enc[b*64+x], msgh[b*16+x])   [512 x 2048]
__global__ void build_cc1(const float* __restrict__ enc, const float* __restrict__ msgh,
                          float* __restrict__ Cc1)
{
    int i = blockIdx.x * 256 + threadIdx.x;     // over 512*512 float4
    if (i >= 512 * 512) return;
    int r = i >> 9, q = i & 511;
    int b = r >> 4, x = r & 15;
    float4 v;
    if (q < 256) v = ((const float4*)enc)[(b * 64 + x) * 256 + q];
    else         v = ((const float4*)msgh)[r * 256 + (q - 256)];
    ((float4*)Cc1)[i] = v;
}

// Cc2[b*64+n] = concat(n<16 ? ench[b*16+n] : enc[b*64+n], msgo[b*64+n])  [2048 x 2048]
__global__ void build_cc2(const float* __restrict__ enc, const float* __restrict__ ench,
                          const float* __restrict__ msgo, float* __restrict__ Cc2)
{
    int i = blockIdx.x * 256 + threadIdx.x;     // over 2048*512 float4
    if (i >= 2048 * 512) return;
    int r = i >> 9, q = i & 511;
    int b = r >> 6, n = r & 63;
    float4 v;
    if (q < 256) {
        if (n < 16) v = ((const float4*)ench)[(b * 16 + n) * 256 + q];
        else        v = ((const float4*)enc)[r * 256 + q];
    } else {
        v = ((const float4*)msgo)[r * 256 + (q - 256)];
    }
    ((float4*)Cc2)[i] = v;
}

// ---------------------------------------------------------------------------
__global__ void pair_out(const float* __restrict__ enc, float* __restrict__ out0)
{
    int i = blockIdx.x * 256 + threadIdx.x;     // over 32256*512 float4
    if (i >= BM * 512) return;
    int r = i >> 9, q = i & 511;
    int b = r / M_, m = r % M_;
    int x = m / 63, j = m % 63;
    int y = j + (j >= x ? 1 : 0);
    const float4* e4 = (const float4*)enc;
    float4 v = (q < 256) ? e4[(b * 64 + x) * 256 + q]
                         : e4[(b * 64 + y) * 256 + (q - 256)];
    ((float4*)out0)[i] = v;
}

__global__ void coords_out(const float* __restrict__ coords,
                           float* __restrict__ out1, float* __restrict__ out2)
{
    int r = blockIdx.x * 256 + threadIdx.x;
    if (r >= BM) return;
    int b = r / M_, m = r % M_;
    int x = m / 63, j = m % 63;
    int y = j + (j >= x ? 1 : 0);
    const float4* c4 = (const float4*)coords;
    ((float4*)out1)[r] = c4[b * 64 + x];
    ((float4*)out2)[r] = c4[b * 64 + y];
}

__device__ __forceinline__ float lis_f(float x)
{
    return 8.3f / (1.f + expf(12.f - 10.f * x));
}

__global__ void prior_out(const float* __restrict__ Aw, const int* __restrict__ labels,
                          const float* __restrict__ scores, float* __restrict__ out3)
{
    int i = blockIdx.x * 256 + threadIdx.x;     // over BM*117
    if (i >= BM * NCLS) return;
    int r = i / NCLS, c = i % NCLS;
    int b = r / M_, m = r % M_;
    int x = m / 63, j = m % 63;
    int y = j + (j >= x ? 1 : 0);
    int lab = labels[b * 64 + y];
    float val = 0.f;
    if (c == lab) {
        float sx = scores[b * 64 + x], sy = scores[b * 64 + y];
        val = Aw[(b * NH + x) * N_ + y] * lis_f(sx) * lis_f(sy);
    }
    out3[i] = val;
}

// ---------------------------------------------------------------------------
extern "C" void kernel_launch(void* const* d_in, const int* in_sizes, int n_in,
                              void* d_out, int out_size, void* d_ws, size_t ws_size,
                              hipStream_t stream)
{
    const float* box_features = (const float*)d_in[0];
    const float* box_coords   = (const float*)d_in[1];
    const int*   box_labels   = (const int*)d_in[2];
    const float* box_scores   = (const float*)d_in[3];
    const float* W1  = (const float*)d_in[4];
    const float* b1  = (const float*)d_in[5];
    const float* W2  = (const float*)d_in[6];
    const float* b2  = (const float*)d_in[7];
    const float* W3  = (const float*)d_in[8];
    const float* b3  = (const float*)d_in[9];
    const float* Ws  = (const float*)d_in[10];
    const float* bs  = (const float*)d_in[11];
    const float* Wo  = (const float*)d_in[12];
    const float* bo  = (const float*)d_in[13];
    const float* Wsu = (const float*)d_in[14];
    const float* Wou = (const float*)d_in[15];

    float* ws   = (float*)d_ws;
    float* encA = ws;            ws += (size_t)B_ * N_ * R_;     // 2097152
    float* encB = ws;            ws += (size_t)B_ * N_ * R_;
    float* Hg   = ws;            ws += (size_t)B_ * NH * R_;     // 524288
    float* U    = ws;            ws += (size_t)B_ * NH * REP;
    float* V    = ws;            ws += (size_t)B_ * N_ * REP;
    float* wpart= ws;            ws += (size_t)4 * BM;           // 129024
    float* Aw   = ws;            ws += (size_t)B_ * NH * N_;     // 32768
    float* Go   = ws;            ws += (size_t)B_ * N_ * REP;
    float* msgh = ws;            ws += (size_t)B_ * NH * REP;
    float* Cc1  = ws;            ws += (size_t)B_ * NH * 2048;   // 1048576
    float* ench = ws;            ws += (size_t)B_ * NH * R_;
    float* Gs   = ws;            ws += (size_t)B_ * NH * REP;
    float* msgo = ws;            ws += (size_t)B_ * N_ * REP;
    float* Cc2  = ws;            ws += (size_t)B_ * N_ * 2048;   // 4194304

    float* out0 = (float*)d_out;                       // pair [32256, 2048]
    float* out1 = out0 + (size_t)BM * 2048;            // bh   [32,1008,4]
    float* out2 = out1 + (size_t)BM * 4;               // bo   [32,1008,4]
    float* out3 = out2 + (size_t)BM * 4;               // prior[32256, 117]

    // enc <- box_features
    copy_f4<<<2048, 256, 0, stream>>>((const float4*)box_features, (float4*)encA,
                                      B_ * N_ * R_ / 4);

    for (int it = 0; it < 2; ++it) {
        const float* encIn = (it == 0) ? encA : encB;
        float*       encOut= (it == 0) ? encB : encA;

        build_hg<<<512, 256, 0, stream>>>(encIn, Hg);
        // U = Hg @ W1_top + b1
        gemm128<<<dim3(8, 4), 256, 0, stream>>>(Hg, W1, b1, U, 1024, 1024, 0);
        // V = enc @ W1_bot
        gemm128<<<dim3(8, 16), 256, 0, stream>>>(encIn, W1 + 1024 * 1024, nullptr, V,
                                                 1024, 1024, 0);
        // big fused pair MLP -> wpart
        pair_gemm<<<dim3(4, 252), 256, 0, stream>>>(U, V, W2, b2, W3, wpart);
        zero_aw<<<128, 256, 0, stream>>>(Aw);
        reduce_w<<<126, 256, 0, stream>>>(wpart, b3, Aw);
        // Go = relu(enc @ Wo + bo)
        gemm128<<<dim3(8, 16), 256, 0, stream>>>(encIn, Wo, bo, Go, 1024, 1024, 1);
        msgh_kernel<<<dim3(32, 8), 128, 0, stream>>>(Aw, Go, msgh);
        build_cc1<<<1024, 256, 0, stream>>>(encIn, msgh, Cc1);
        // ench = Cc1 @ Wsu
        gemm128<<<dim3(8, 4), 256, 0, stream>>>(Cc1, Wsu, nullptr, ench, 2048, 1024, 0);
        // Gs = relu(ench @ Ws + bs)
        gemm128<<<dim3(8, 4), 256, 0, stream>>>(ench, Ws, bs, Gs, 1024, 1024, 1);
        msgo_kernel<<<dim3(32, 8), 128, 0, stream>>>(Aw, Gs, msgo);
        build_cc2<<<4096, 256, 0, stream>>>(encIn, ench, msgo, Cc2);
        // encOut = Cc2 @ Wou
        gemm128<<<dim3(8, 16), 256, 0, stream>>>(Cc2, Wou, nullptr, encOut, 2048, 1024, 0);
    }

    // outputs (final enc is encA after 2 iterations; Aw holds last-iter A)
    pair_out<<<64512, 256, 0, stream>>>(encA, out0);
    coords_out<<<126, 256, 0, stream>>>(box_coords, out1, out2);
    prior_out<<<14742, 256, 0, stream>>>(Aw, box_labels, box_scores, out3);
}

// Round 2
// 1277.940 us; speedup vs baseline: 2.4674x; 2.4674x over previous
//
#include <hip/hip_runtime.h>

#define B_   32
#define N_   64
#define NH   16
#define R_   1024
#define REP  1024
#define REP2 512
#define M_   1008           // 16*63
#define BM   (B_ * M_)      // 32256
#define NCLS 117

typedef short bhalf8 __attribute__((ext_vector_type(8)));   // 8 bf16 (4 VGPRs)
typedef float f32x4  __attribute__((ext_vector_type(4)));   // MFMA acc

__device__ __forceinline__ unsigned short f2bf(float f)
{
    union { float f; unsigned int u; } x; x.f = f;
    unsigned int r = x.u + 0x7FFFu + ((x.u >> 16) & 1u);    // round-nearest-even
    return (unsigned short)(r >> 16);
}

// pack 4 floats -> 4 bf16 in one uint2
__device__ __forceinline__ uint2 pack4(float4 v)
{
    uint2 o;
    o.x = (unsigned)f2bf(v.x) | ((unsigned)f2bf(v.y) << 16);
    o.y = (unsigned)f2bf(v.z) | ((unsigned)f2bf(v.w) << 16);
    return o;
}

// ---------------------------------------------------------------------------
// weight prep: out[n*K + k] = bf16(in[k*N + n]);  grid (K/32, N/32), block 256
// ---------------------------------------------------------------------------
__global__ void transpose_bf(const float* __restrict__ in, unsigned short* __restrict__ out,
                             int K, int N)
{
    __shared__ float t[32][33];
    int tx = threadIdx.x & 31, ty = threadIdx.x >> 5;
    int k0 = blockIdx.x * 32, n0 = blockIdx.y * 32;
#pragma unroll
    for (int r = 0; r < 4; ++r)
        t[ty + r * 8][tx] = in[(size_t)(k0 + ty + r * 8) * N + n0 + tx];
    __syncthreads();
#pragma unroll
    for (int r = 0; r < 4; ++r)
        out[(size_t)(n0 + ty + r * 8) * K + k0 + tx] = f2bf(t[tx][ty + r * 8]);
}

// ---------------------------------------------------------------------------
// bf16 MFMA GEMM: C[M,N] = opt_relu(A_f32[M,K] @ (Bt_bf16[N,K])^T + bias)
// 128x128 tile, BK=32.  grid (N/128, M/128), block 256 (4 waves, 64x64 each).
// ---------------------------------------------------------------------------
#define LDSTR 40    // LDS row stride in bf16 elems (80 B, 16B-aligned, conflict-light)

__global__ __launch_bounds__(256)
void gemm_bf(const float* __restrict__ A, const unsigned short* __restrict__ Bt,
             const float* __restrict__ bias, float* __restrict__ C,
             int K, int Nc, int doRelu)
{
    __shared__ unsigned short As[128 * LDSTR];
    __shared__ unsigned short Bs[128 * LDSTR];
    const int tid  = threadIdx.x;
    const int lane = tid & 63, wave = tid >> 6;
    const int wm = wave & 1, wn = wave >> 1;
    const int l15 = lane & 15, lk = lane >> 4;
    const int row0 = blockIdx.y * 128, col0 = blockIdx.x * 128;

    const int srow = tid >> 1;      // 0..127
    const int skh  = tid & 1;       // which 16-elem k half
    const float*          Ap = A  + (size_t)(row0 + srow) * K + skh * 16;
    const unsigned short* Bp = Bt + (size_t)(col0 + srow) * K + skh * 16;
    unsigned short* AsW = As + srow * LDSTR + skh * 16;
    unsigned short* BsW = Bs + srow * LDSTR + skh * 16;

    f32x4 acc[4][4];
#pragma unroll
    for (int i = 0; i < 4; ++i)
#pragma unroll
    for (int j = 0; j < 4; ++j) acc[i][j] = (f32x4)0.f;

    for (int k0 = 0; k0 < K; k0 += 32) {
        float4 a0 = *(const float4*)(Ap + k0);
        float4 a1 = *(const float4*)(Ap + k0 + 4);
        float4 a2 = *(const float4*)(Ap + k0 + 8);
        float4 a3 = *(const float4*)(Ap + k0 + 12);
        uint4  b0 = *(const uint4*)(Bp + k0);
        uint4  b1 = *(const uint4*)(Bp + k0 + 8);
        uint2 p0 = pack4(a0), p1 = pack4(a1), p2 = pack4(a2), p3 = pack4(a3);
        __syncthreads();
        *(uint4*)(AsW)     = make_uint4(p0.x, p0.y, p1.x, p1.y);
        *(uint4*)(AsW + 8) = make_uint4(p2.x, p2.y, p3.x, p3.y);
        *(uint4*)(BsW)     = b0;
        *(uint4*)(BsW + 8) = b1;
        __syncthreads();
        bhalf8 af[4], bf4[4];
#pragma unroll
        for (int mt = 0; mt < 4; ++mt)
            af[mt] = *(bhalf8*)&As[(wm * 64 + mt * 16 + l15) * LDSTR + lk * 8];
#pragma unroll
        for (int nt = 0; nt < 4; ++nt)
            bf4[nt] = *(bhalf8*)&Bs[(wn * 64 + nt * 16 + l15) * LDSTR + lk * 8];
#pragma unroll
        for (int mt = 0; mt < 4; ++mt)
#pragma unroll
        for (int nt = 0; nt < 4; ++nt)
            acc[mt][nt] = __builtin_amdgcn_mfma_f32_16x16x32_bf16(af[mt], bf4[nt],
                                                                  acc[mt][nt], 0, 0, 0);
    }

#pragma unroll
    for (int mt = 0; mt < 4; ++mt)
#pragma unroll
    for (int r = 0; r < 4; ++r) {
        int row = row0 + wm * 64 + mt * 16 + lk * 4 + r;
#pragma unroll
        for (int nt = 0; nt < 4; ++nt) {
            int col = col0 + wn * 64 + nt * 16 + l15;
            float v = acc[mt][nt][r];
            if (bias) v += bias[col];
            if (doRelu) v = fmaxf(v, 0.f);
            C[(size_t)row * Nc + col] = v;
        }
    }
}

// ---------------------------------------------------------------------------
// fused pair MLP: A-rows = relu(U[b,x]+V[b,y]) built on the fly (bf16),
// GEMM vs W2t, epilogue fuses relu(+b2) and the W3 dot -> wpart[chunk][row].
// grid (4, 252), block 256.
// ---------------------------------------------------------------------------
__global__ __launch_bounds__(256)
void pair_bf(const float* __restrict__ U, const float* __restrict__ V,
             const unsigned short* __restrict__ W2t, const float* __restrict__ b2,
             const float* __restrict__ W3f, float* __restrict__ wpart)
{
    __shared__ unsigned short As[128 * LDSTR];
    __shared__ unsigned short Bs[128 * LDSTR];
    __shared__ float red[2][128];
    const int tid  = threadIdx.x;
    const int lane = tid & 63, wave = tid >> 6;
    const int wm = wave & 1, wn = wave >> 1;
    const int l15 = lane & 15, lk = lane >> 4;
    const int row0 = blockIdx.y * 128, col0 = blockIdx.x * 128;

    const int srow = tid >> 1;
    const int skh  = tid & 1;
    int rg = row0 + srow;
    int b  = rg / M_, m = rg % M_;
    int x  = m / 63, jj = m % 63;
    int y  = jj + (jj >= x ? 1 : 0);
    const float* Up = U + ((size_t)b * NH + x) * REP + skh * 16;
    const float* Vp = V + ((size_t)b * N_ + y) * REP + skh * 16;
    const unsigned short* Bp = W2t + (size_t)(col0 + srow) * REP + skh * 16;
    unsigned short* AsW = As + srow * LDSTR + skh * 16;
    unsigned short* BsW = Bs + srow * LDSTR + skh * 16;

    f32x4 acc[4][4];
#pragma unroll
    for (int i = 0; i < 4; ++i)
#pragma unroll
    for (int j = 0; j < 4; ++j) acc[i][j] = (f32x4)0.f;

    for (int k0 = 0; k0 < REP; k0 += 32) {
        float4 h[4];
#pragma unroll
        for (int q = 0; q < 4; ++q) {
            float4 u = *(const float4*)(Up + k0 + q * 4);
            float4 v = *(const float4*)(Vp + k0 + q * 4);
            h[q].x = fmaxf(u.x + v.x, 0.f); h[q].y = fmaxf(u.y + v.y, 0.f);
            h[q].z = fmaxf(u.z + v.z, 0.f); h[q].w = fmaxf(u.w + v.w, 0.f);
        }
        uint4 b0 = *(const uint4*)(Bp + k0);
        uint4 b1 = *(const uint4*)(Bp + k0 + 8);
        uint2 p0 = pack4(h[0]), p1 = pack4(h[1]), p2 = pack4(h[2]), p3 = pack4(h[3]);
        __syncthreads();
        *(uint4*)(AsW)     = make_uint4(p0.x, p0.y, p1.x, p1.y);
        *(uint4*)(AsW + 8) = make_uint4(p2.x, p2.y, p3.x, p3.y);
        *(uint4*)(BsW)     = b0;
        *(uint4*)(BsW + 8) = b1;
        __syncthreads();
        bhalf8 af[4], bf4[4];
#pragma unroll
        for (int mt = 0; mt < 4; ++mt)
            af[mt] = *(bhalf8*)&As[(wm * 64 + mt * 16 + l15) * LDSTR + lk * 8];
#pragma unroll
        for (int nt = 0; nt < 4; ++nt)
            bf4[nt] = *(bhalf8*)&Bs[(wn * 64 + nt * 16 + l15) * LDSTR + lk * 8];
#pragma unroll
        for (int mt = 0; mt < 4; ++mt)
#pragma unroll
        for (int nt = 0; nt < 4; ++nt)
            acc[mt][nt] = __builtin_amdgcn_mfma_f32_16x16x32_bf16(af[mt], bf4[nt],
                                                                  acc[mt][nt], 0, 0, 0);
    }

    // epilogue: h2 = relu(acc + b2[col]); partial = h2 . W3[col] over 128 cols
    float b2v[4], w3v[4];
#pragma unroll
    for (int nt = 0; nt < 4; ++nt) {
        int col = col0 + wn * 64 + nt * 16 + l15;
        b2v[nt] = b2[col];
        w3v[nt] = W3f[col];
    }
#pragma unroll
    for (int mt = 0; mt < 4; ++mt)
#pragma unroll
    for (int r = 0; r < 4; ++r) {
        int rloc = wm * 64 + mt * 16 + lk * 4 + r;
        float p = 0.f;
#pragma unroll
        for (int nt = 0; nt < 4; ++nt)
            p += fmaxf(acc[mt][nt][r] + b2v[nt], 0.f) * w3v[nt];
        p += __shfl_xor(p, 1); p += __shfl_xor(p, 2);
        p += __shfl_xor(p, 4); p += __shfl_xor(p, 8);
        if (l15 == 0) red[wn][rloc] = p;
    }
    __syncthreads();
    if (tid < 128)
        wpart[blockIdx.x * BM + row0 + tid] = red[0][tid] + red[1][tid];
}

// ---------------------------------------------------------------------------
__global__ void zero_aw(float* __restrict__ Aw)
{
    int i = blockIdx.x * 256 + threadIdx.x;
    if (i < B_ * NH * N_) Aw[i] = 0.f;
}

__global__ void reduce_w(const float* __restrict__ wpart, const float* __restrict__ b3,
                         float* __restrict__ Aw)
{
    int r = blockIdx.x * 256 + threadIdx.x;
    if (r >= BM) return;
    float s = b3[0];
#pragma unroll
    for (int c = 0; c < 4; ++c) s += wpart[c * BM + r];
    float sig = 1.f / (1.f + expf(-s));
    int b = r / M_, m = r % M_;
    int x = m / 63, j = m % 63;
    int y = j + (j >= x ? 1 : 0);
    Aw[(b * NH + x) * N_ + y] = sig;
}

// msg_h[b] = A[b] @ Go[b]   ([16,64]@[64,1024]);  grid (32, 8), block 128
__global__ __launch_bounds__(128)
void msgh_kernel(const float* __restrict__ Aw, const float* __restrict__ Go,
                 float* __restrict__ msgh)
{
    __shared__ float Al[NH * N_];
    __shared__ float Gl[N_][128];
    int b = blockIdx.x, c0 = blockIdx.y * 128, t = threadIdx.x;
    for (int i = t; i < NH * N_; i += 128) Al[i] = Aw[b * NH * N_ + i];
    for (int y = 0; y < N_; ++y) Gl[y][t] = Go[((size_t)(b * N_ + y)) * REP + c0 + t];
    __syncthreads();
    for (int x = 0; x < NH; ++x) {
        float s = 0.f;
#pragma unroll 8
        for (int y = 0; y < N_; ++y) s += Al[x * N_ + y] * Gl[y][t];
        msgh[((size_t)(b * NH + x)) * REP + c0 + t] = s;
    }
}

// msg_o[b] = A[b]^T @ Gs[b]  ([64,16]@[16,1024]);  grid (32, 8), block 128
__global__ __launch_bounds__(128)
void msgo_kernel(const float* __restrict__ Aw, const float* __restrict__ Gs,
                 float* __restrict__ msgo)
{
    __shared__ float Al[NH * N_];
    __shared__ float Gl[NH][128];
    int b = blockIdx.x, c0 = blockIdx.y * 128, t = threadIdx.x;
    for (int i = t; i < NH * N_; i += 128) Al[i] = Aw[b * NH * N_ + i];
    for (int x = 0; x < NH; ++x) Gl[x][t] = Gs[((size_t)(b * NH + x)) * REP + c0 + t];
    __syncthreads();
    for (int y = 0; y < N_; ++y) {
        float s = 0.f;
#pragma unroll
        for (int x = 0; x < NH; ++x) s += Al[x * N_ + y] * Gl[x][t];
        msgo[((size_t)(b * N_ + y)) * REP + c0 + t] = s;
    }
}

// ---------------------------------------------------------------------------
// gather humans: Hg[b*16+x] = enc[b*64+x]
__global__ void build_hg(const float* __restrict__ enc, float* __restrict__ Hg)
{
    int i = blockIdx.x * 256 + threadIdx.x;     // over 512*256 float4
    if (i >= 512 * 256) return;
    int r = i >> 8, q = i & 255;
    int b = r >> 4, x = r & 15;
    ((float4*)Hg)[i] = ((const float4*)enc)[(b * 64 + x) * 256 + q];
}

// Cc1[b*16+x] = concat(enc[b*64+x], msgh[b*16+x])   [512 x 2048]
__global__ void build_cc1(const float* __restrict__ enc, const float* __restrict__ msgh,
                          float* __restrict__ Cc1)
{
    int i = blockIdx.x * 256 + threadIdx.x;     // over 512*512 float4
    if (i >= 512 * 512) return;
    int r = i >> 9, q = i & 511;
    int b = r >> 4, x = r & 15;
    float4 v;
    if (q < 256) v = ((const float4*)enc)[(b * 64 + x) * 256 + q];
    else         v = ((const float4*)msgh)[r * 256 + (q - 256)];
    ((float4*)Cc1)[i] = v;
}

// Cc2[b*64+n] = concat(n<16 ? ench[b*16+n] : enc[b*64+n], msgo[b*64+n])  [2048 x 2048]
__global__ void build_cc2(const float* __restrict__ enc, const float* __restrict__ ench,
                          const float* __restrict__ msgo, float* __restrict__ Cc2)
{
    int i = blockIdx.x * 256 + threadIdx.x;     // over 2048*512 float4
    if (i >= 2048 * 512) return;
    int r = i >> 9, q = i & 511;
    int b = r >> 6, n = r & 63;
    float4 v;
    if (q < 256) {
        if (n < 16) v = ((const float4*)ench)[(b * 16 + n) * 256 + q];
        else        v = ((const float4*)enc)[r * 256 + q];
    } else {
        v = ((const float4*)msgo)[r * 256 + (q - 256)];
    }
    ((float4*)Cc2)[i] = v;
}

// ---------------------------------------------------------------------------
__global__ void pair_out(const float* __restrict__ enc, float* __restrict__ out0)
{
    int i = blockIdx.x * 256 + threadIdx.x;     // over 32256*512 float4
    if (i >= BM * 512) return;
    int r = i >> 9, q = i & 511;
    int b = r / M_, m = r % M_;
    int x = m / 63, j = m % 63;
    int y = j + (j >= x ? 1 : 0);
    const float4* e4 = (const float4*)enc;
    float4 v = (q < 256) ? e4[(b * 64 + x) * 256 + q]
                         : e4[(b * 64 + y) * 256 + (q - 256)];
    ((float4*)out0)[i] = v;
}

__global__ void coords_out(const float* __restrict__ coords,
                           float* __restrict__ out1, float* __restrict__ out2)
{
    int r = blockIdx.x * 256 + threadIdx.x;
    if (r >= BM) return;
    int b = r / M_, m = r % M_;
    int x = m / 63, j = m % 63;
    int y = j + (j >= x ? 1 : 0);
    const float4* c4 = (const float4*)coords;
    ((float4*)out1)[r] = c4[b * 64 + x];
    ((float4*)out2)[r] = c4[b * 64 + y];
}

__device__ __forceinline__ float lis_f(float x)
{
    return 8.3f / (1.f + expf(12.f - 10.f * x));
}

__global__ void prior_out(const float* __restrict__ Aw, const int* __restrict__ labels,
                          const float* __restrict__ scores, float* __restrict__ out3)
{
    int i = blockIdx.x * 256 + threadIdx.x;     // over BM*117
    if (i >= BM * NCLS) return;
    int r = i / NCLS, c = i % NCLS;
    int b = r / M_, m = r % M_;
    int x = m / 63, j = m % 63;
    int y = j + (j >= x ? 1 : 0);
    int lab = labels[b * 64 + y];
    float val = 0.f;
    if (c == lab) {
        float sx = scores[b * 64 + x], sy = scores[b * 64 + y];
        val = Aw[(b * NH + x) * N_ + y] * lis_f(sx) * lis_f(sy);
    }
    out3[i] = val;
}

// ---------------------------------------------------------------------------
extern "C" void kernel_launch(void* const* d_in, const int* in_sizes, int n_in,
                              void* d_out, int out_size, void* d_ws, size_t ws_size,
                              hipStream_t stream)
{
    const float* box_features = (const float*)d_in[0];
    const float* box_coords   = (const float*)d_in[1];
    const int*   box_labels   = (const int*)d_in[2];
    const float* box_scores   = (const float*)d_in[3];
    const float* W1  = (const float*)d_in[4];
    const float* b1  = (const float*)d_in[5];
    const float* W2  = (const float*)d_in[6];
    const float* b2  = (const float*)d_in[7];
    const float* W3  = (const float*)d_in[8];
    const float* b3  = (const float*)d_in[9];
    const float* Ws  = (const float*)d_in[10];
    const float* bs  = (const float*)d_in[11];
    const float* Wo  = (const float*)d_in[12];
    const float* bo  = (const float*)d_in[13];
    const float* Wsu = (const float*)d_in[14];
    const float* Wou = (const float*)d_in[15];

    float* ws   = (float*)d_ws;
    float* encA = ws;            ws += (size_t)B_ * N_ * R_;     // 2M floats
    float* encB = ws;            ws += (size_t)B_ * N_ * R_;
    float* Hg   = ws;            ws += (size_t)B_ * NH * R_;     // 0.5M
    float* P    = ws;            ws += (size_t)B_ * N_ * 2048;   // 4M: U|V then Cc2
    float* U    = P;                                             // 0.5M
    float* V    = P + (size_t)B_ * NH * REP;                     // 2M
    float* Cc2  = P;
    float* wpart= ws;            ws += (size_t)4 * BM;           // 129024
    float* Aw   = ws;            ws += (size_t)B_ * NH * N_;     // 32768
    float* Go   = ws;            ws += (size_t)B_ * N_ * REP;    // 2M: Go then Cc1
    float* Cc1  = Go;                                            // 1M (dead Go)
    float* ench = ws;            ws += (size_t)B_ * NH * R_;     // 0.5M
    float* Gs   = ws;            ws += (size_t)B_ * NH * REP;    // 0.5M
    float* msgh = ws;            ws += (size_t)B_ * NH * REP;    // 0.5M
    float* msgo = ws;            ws += (size_t)B_ * N_ * REP;    // 2M

    unsigned short* wsu = (unsigned short*)ws;
    unsigned short* W1tt = wsu;  wsu += (size_t)1024 * 1024;
    unsigned short* W1tb = wsu;  wsu += (size_t)1024 * 1024;
    unsigned short* W2t  = wsu;  wsu += (size_t)512 * 1024;
    unsigned short* Wot  = wsu;  wsu += (size_t)1024 * 1024;
    unsigned short* Wst  = wsu;  wsu += (size_t)1024 * 1024;
    unsigned short* Wsut = wsu;  wsu += (size_t)1024 * 2048;
    unsigned short* Wout = wsu;  wsu += (size_t)1024 * 2048;

    float* out0 = (float*)d_out;                       // pair [32256, 2048]
    float* out1 = out0 + (size_t)BM * 2048;            // bh   [32,1008,4]
    float* out2 = out1 + (size_t)BM * 4;               // bo   [32,1008,4]
    float* out3 = out2 + (size_t)BM * 4;               // prior[32256, 117]

    // ---- weight prep (bf16, transposed to [N][K]) ----
    transpose_bf<<<dim3(32, 32), 256, 0, stream>>>(W1, W1tt, 1024, 1024);
    transpose_bf<<<dim3(32, 32), 256, 0, stream>>>(W1 + 1024 * 1024, W1tb, 1024, 1024);
    transpose_bf<<<dim3(32, 16), 256, 0, stream>>>(W2, W2t, 1024, 512);
    transpose_bf<<<dim3(32, 32), 256, 0, stream>>>(Wo, Wot, 1024, 1024);
    transpose_bf<<<dim3(32, 32), 256, 0, stream>>>(Ws, Wst, 1024, 1024);
    transpose_bf<<<dim3(64, 32), 256, 0, stream>>>(Wsu, Wsut, 2048, 1024);
    transpose_bf<<<dim3(64, 32), 256, 0, stream>>>(Wou, Wout, 2048, 1024);

    for (int it = 0; it < 2; ++it) {
        const float* encIn = (it == 0) ? box_features : encB;
        float*       encOut= (it == 0) ? encB : encA;

        build_hg<<<512, 256, 0, stream>>>(encIn, Hg);
        // U = Hg @ W1_top + b1
        gemm_bf<<<dim3(8, 4), 256, 0, stream>>>(Hg, W1tt, b1, U, 1024, 1024, 0);
        // V = enc @ W1_bot
        gemm_bf<<<dim3(8, 16), 256, 0, stream>>>(encIn, W1tb, nullptr, V, 1024, 1024, 0);
        // fused pair MLP -> wpart
        pair_bf<<<dim3(4, 252), 256, 0, stream>>>(U, V, W2t, b2, W3, wpart);
        zero_aw<<<128, 256, 0, stream>>>(Aw);
        reduce_w<<<126, 256, 0, stream>>>(wpart, b3, Aw);
        // Go = relu(enc @ Wo + bo)
        gemm_bf<<<dim3(8, 16), 256, 0, stream>>>(encIn, Wot, bo, Go, 1024, 1024, 1);
        msgh_kernel<<<dim3(32, 8), 128, 0, stream>>>(Aw, Go, msgh);
        build_cc1<<<1024, 256, 0, stream>>>(encIn, msgh, Cc1);
        // ench = Cc1 @ Wsu
        gemm_bf<<<dim3(8, 4), 256, 0, stream>>>(Cc1, Wsut, nullptr, ench, 2048, 1024, 0);
        // Gs = relu(ench @ Ws + bs)
        gemm_bf<<<dim3(8, 4), 256, 0, stream>>>(ench, Wst, bs, Gs, 1024, 1024, 1);
        msgo_kernel<<<dim3(32, 8), 128, 0, stream>>>(Aw, Gs, msgo);
        build_cc2<<<4096, 256, 0, stream>>>(encIn, ench, msgo, Cc2);
        // encOut = Cc2 @ Wou
        gemm_bf<<<dim3(8, 16), 256, 0, stream>>>(Cc2, Wout, nullptr, encOut, 2048, 1024, 0);
    }

    // outputs (final enc = encA; Aw holds last-iter A)
    pair_out<<<64512, 256, 0, stream>>>(encA, out0);
    coords_out<<<126, 256, 0, stream>>>(box_coords, out1, out2);
    prior_out<<<14742, 256, 0, stream>>>(Aw, box_labels, box_scores, out3);
}

// Round 3
// 1036.381 us; speedup vs baseline: 3.0425x; 1.2331x over previous
//
#include <hip/hip_runtime.h>

#define B_   32
#define N_   64
#define NH   16
#define R_   1024
#define REP  1024
#define M_   1008           // 16*63
#define BM   (B_ * M_)      // 32256
#define NCLS 117

#define MD_DIRECT 0
#define MD_HG     1   // 512 rows -> enc row b*64 + x
#define MD_CC1    2   // k<1024: enc[b*64+x]; k>=1024: msgh[row]      (512 rows)
#define MD_CC2    3   // k<1024: n<16?ench[b*16+n]:enc[row]; k>=1024: msgo[row] (2048 rows)

typedef short bhalf8 __attribute__((ext_vector_type(8)));   // 8 bf16 (4 VGPRs)
typedef float f32x4  __attribute__((ext_vector_type(4)));   // MFMA acc

typedef __attribute__((address_space(3))) void       lds_t;
typedef const __attribute__((address_space(1))) void gbl_t;
__device__ __forceinline__ void gld16(const void* g, void* l)
{
    __builtin_amdgcn_global_load_lds((gbl_t*)g, (lds_t*)l, 16, 0, 0);
}

__device__ __forceinline__ unsigned short f2bf(float f)
{
    union { float f; unsigned int u; } x; x.f = f;
    unsigned int r = x.u + 0x7FFFu + ((x.u >> 16) & 1u);    // round-nearest-even
    return (unsigned short)(r >> 16);
}
__device__ __forceinline__ float bf2f(unsigned short u)
{
    union { unsigned int i; float f; } x; x.i = ((unsigned int)u) << 16; return x.f;
}
// a,b are two packed bf16 pairs: out = pack(relu(lo(a)+lo(b)), relu(hi(a)+hi(b)))
__device__ __forceinline__ unsigned int addrelu2(unsigned int a, unsigned int b)
{
    float lo = fmaxf(bf2f((unsigned short)(a & 0xffff)) + bf2f((unsigned short)(b & 0xffff)), 0.f);
    float hi = fmaxf(bf2f((unsigned short)(a >> 16))    + bf2f((unsigned short)(b >> 16)),    0.f);
    return (unsigned int)f2bf(lo) | ((unsigned int)f2bf(hi) << 16);
}

// ---------------------------------------------------------------------------
// weight prep: out[n*K + k] = bf16(in[k*N + n]);  grid (K/32, N/32), block 256
// ---------------------------------------------------------------------------
__global__ void transpose_bf(const float* __restrict__ in, unsigned short* __restrict__ out,
                             int K, int N)
{
    __shared__ float t[32][33];
    int tx = threadIdx.x & 31, ty = threadIdx.x >> 5;
    int k0 = blockIdx.x * 32, n0 = blockIdx.y * 32;
#pragma unroll
    for (int r = 0; r < 4; ++r)
        t[ty + r * 8][tx] = in[(size_t)(k0 + ty + r * 8) * N + n0 + tx];
    __syncthreads();
#pragma unroll
    for (int r = 0; r < 4; ++r)
        out[(size_t)(n0 + ty + r * 8) * K + k0 + tx] = f2bf(t[tx][ty + r * 8]);
}

// box_features -> bf16 (8 elems/thread)
__global__ void cvt_bf(const float* __restrict__ in, unsigned short* __restrict__ out)
{
    int i = blockIdx.x * 256 + threadIdx.x;     // over 2M/8 = 256K
    float4 a = ((const float4*)in)[2 * i];
    float4 b = ((const float4*)in)[2 * i + 1];
    uint4 o;
    o.x = (unsigned)f2bf(a.x) | ((unsigned)f2bf(a.y) << 16);
    o.y = (unsigned)f2bf(a.z) | ((unsigned)f2bf(a.w) << 16);
    o.z = (unsigned)f2bf(b.x) | ((unsigned)f2bf(b.y) << 16);
    o.w = (unsigned)f2bf(b.z) | ((unsigned)f2bf(b.w) << 16);
    ((uint4*)out)[i] = o;
}

// ---------------------------------------------------------------------------
// bf16 MFMA GEMM, m97-style staging. A rows mapped per `mode` (gather/concat).
// C = opt_relu(A @ Bt^T + bias) -> Cf (fp32) and/or Cb (bf16).
// 128x128 tile, BK=32, grid (N/128, M/128), block 256.
// ---------------------------------------------------------------------------
__global__ __launch_bounds__(256)
void gemm_bf(const unsigned short* __restrict__ A1, const unsigned short* __restrict__ A2,
             const unsigned short* __restrict__ A3, const unsigned short* __restrict__ Bt,
             const float* __restrict__ bias, float* __restrict__ Cf,
             unsigned short* __restrict__ Cb, int K, int Nc, int doRelu, int mode)
{
    __shared__ unsigned short As[128 * 32];
    __shared__ unsigned short Bs[128 * 32];
    const int tid  = threadIdx.x;
    const int lane = tid & 63, wave = tid >> 6;
    const int wm = wave & 1, wn = wave >> 1;
    const int l15 = lane & 15, lk = lane >> 4;
    const int row0 = blockIdx.y * 128, col0 = blockIdx.x * 128;
    const int kq = (lane & 3) * 8;          // elem offset inside 32-k tile

    const unsigned short* pA1[2];
    const unsigned short* pA2[2];
    const unsigned short* pB[2];
    unsigned short* AsW[2];
    unsigned short* BsW[2];
    const int kSw = (mode >= MD_CC1) ? 1024 : K;
#pragma unroll
    for (int i = 0; i < 2; ++i) {
        int tr = wave * 32 + (lane >> 2) + i * 16;
        int rr = row0 + tr;
        const unsigned short* p1;
        const unsigned short* p2 = nullptr;
        if (mode == MD_DIRECT) {
            p1 = A1 + (size_t)rr * K;
        } else if (mode == MD_HG) {
            int b = rr >> 4, x = rr & 15;
            p1 = A1 + (size_t)(b * 64 + x) * 1024;
        } else if (mode == MD_CC1) {
            int b = rr >> 4, x = rr & 15;
            p1 = A1 + (size_t)(b * 64 + x) * 1024;
            p2 = A2 + (size_t)rr * 1024 - 1024;
        } else {
            int b = rr >> 6, n = rr & 63;
            p1 = (n < 16) ? A3 + (size_t)(b * 16 + n) * 1024
                          : A1 + (size_t)rr * 1024;
            p2 = A2 + (size_t)rr * 1024 - 1024;
        }
        pA1[i] = p1 + kq;
        pA2[i] = p2 ? p2 + kq : nullptr;
        pB[i]  = Bt + (size_t)(col0 + tr) * K + kq;
        AsW[i] = As + wave * 1024 + i * 512 + lane * 8;
        BsW[i] = Bs + wave * 1024 + i * 512 + lane * 8;
    }

    f32x4 acc[4][4];
#pragma unroll
    for (int i = 0; i < 4; ++i)
#pragma unroll
    for (int j = 0; j < 4; ++j) acc[i][j] = (f32x4)0.f;

    for (int k0 = 0; k0 < K; k0 += 32) {
        const unsigned short* a0 = (k0 < kSw) ? pA1[0] : pA2[0];
        const unsigned short* a1 = (k0 < kSw) ? pA1[1] : pA2[1];
        __syncthreads();
        gld16(a0 + k0,    AsW[0]);
        gld16(a1 + k0,    AsW[1]);
        gld16(pB[0] + k0, BsW[0]);
        gld16(pB[1] + k0, BsW[1]);
        __syncthreads();
        bhalf8 af[4], bf4[4];
#pragma unroll
        for (int mt = 0; mt < 4; ++mt)
            af[mt] = *(bhalf8*)&As[(wm * 64 + mt * 16 + l15) * 32 + lk * 8];
#pragma unroll
        for (int nt = 0; nt < 4; ++nt)
            bf4[nt] = *(bhalf8*)&Bs[(wn * 64 + nt * 16 + l15) * 32 + lk * 8];
#pragma unroll
        for (int mt = 0; mt < 4; ++mt)
#pragma unroll
        for (int nt = 0; nt < 4; ++nt)
            acc[mt][nt] = __builtin_amdgcn_mfma_f32_16x16x32_bf16(af[mt], bf4[nt],
                                                                  acc[mt][nt], 0, 0, 0);
    }

#pragma unroll
    for (int mt = 0; mt < 4; ++mt)
#pragma unroll
    for (int r = 0; r < 4; ++r) {
        int row = row0 + wm * 64 + mt * 16 + lk * 4 + r;
#pragma unroll
        for (int nt = 0; nt < 4; ++nt) {
            int col = col0 + wn * 64 + nt * 16 + l15;
            float v = acc[mt][nt][r];
            if (bias) v += bias[col];
            if (doRelu) v = fmaxf(v, 0.f);
            if (Cf) Cf[(size_t)row * Nc + col] = v;
            if (Cb) Cb[(size_t)row * Nc + col] = f2bf(v);
        }
    }
}

// ---------------------------------------------------------------------------
// fused pair MLP: A-rows = relu(U[b,x]+V[b,y]) (bf16 in, built on the fly),
// GEMM vs W2t, epilogue fuses relu(+b2) + W3 dot -> wpart[chunk][row].
// grid (4, 252), block 256.
// ---------------------------------------------------------------------------
__global__ __launch_bounds__(256)
void pair_bf(const unsigned short* __restrict__ U, const unsigned short* __restrict__ V,
             const unsigned short* __restrict__ W2t, const float* __restrict__ b2,
             const float* __restrict__ W3f, float* __restrict__ wpart)
{
    __shared__ unsigned short As[128 * 32];
    __shared__ unsigned short Bs[128 * 32];
    __shared__ float red[2][128];
    const int tid  = threadIdx.x;
    const int lane = tid & 63, wave = tid >> 6;
    const int wm = wave & 1, wn = wave >> 1;
    const int l15 = lane & 15, lk = lane >> 4;
    const int row0 = blockIdx.y * 128, col0 = blockIdx.x * 128;

    // A staging: thread covers row srow, elems [skh*16, skh*16+16)
    const int srow = tid >> 1, skh = tid & 1;
    int rg = row0 + srow;
    int b  = rg / M_, m = rg % M_;
    int x  = m / 63, jj = m % 63;
    int y  = jj + (jj >= x ? 1 : 0);
    const unsigned short* Up = U + ((size_t)b * NH + x) * REP + skh * 16;
    const unsigned short* Vp = V + ((size_t)b * N_ + y) * REP + skh * 16;
    unsigned short* AsW = As + srow * 32 + skh * 16;

    // B staging via global_load_lds (same pattern as gemm_bf)
    const int kq = (lane & 3) * 8;
    const unsigned short* pB[2];
    unsigned short* BsW[2];
#pragma unroll
    for (int i = 0; i < 2; ++i) {
        int tr = wave * 32 + (lane >> 2) + i * 16;
        pB[i]  = W2t + (size_t)(col0 + tr) * REP + kq;
        BsW[i] = Bs + wave * 1024 + i * 512 + lane * 8;
    }

    f32x4 acc[4][4];
#pragma unroll
    for (int i = 0; i < 4; ++i)
#pragma unroll
    for (int j = 0; j < 4; ++j) acc[i][j] = (f32x4)0.f;

    for (int k0 = 0; k0 < REP; k0 += 32) {
        uint4 uu0 = *(const uint4*)(Up + k0);
        uint4 uu1 = *(const uint4*)(Up + k0 + 8);
        uint4 vv0 = *(const uint4*)(Vp + k0);
        uint4 vv1 = *(const uint4*)(Vp + k0 + 8);
        uint4 h0, h1;
        h0.x = addrelu2(uu0.x, vv0.x); h0.y = addrelu2(uu0.y, vv0.y);
        h0.z = addrelu2(uu0.z, vv0.z); h0.w = addrelu2(uu0.w, vv0.w);
        h1.x = addrelu2(uu1.x, vv1.x); h1.y = addrelu2(uu1.y, vv1.y);
        h1.z = addrelu2(uu1.z, vv1.z); h1.w = addrelu2(uu1.w, vv1.w);
        __syncthreads();
        *(uint4*)(AsW)     = h0;
        *(uint4*)(AsW + 8) = h1;
        gld16(pB[0] + k0, BsW[0]);
        gld16(pB[1] + k0, BsW[1]);
        __syncthreads();
        bhalf8 af[4], bf4[4];
#pragma unroll
        for (int mt = 0; mt < 4; ++mt)
            af[mt] = *(bhalf8*)&As[(wm * 64 + mt * 16 + l15) * 32 + lk * 8];
#pragma unroll
        for (int nt = 0; nt < 4; ++nt)
            bf4[nt] = *(bhalf8*)&Bs[(wn * 64 + nt * 16 + l15) * 32 + lk * 8];
#pragma unroll
        for (int mt = 0; mt < 4; ++mt)
#pragma unroll
        for (int nt = 0; nt < 4; ++nt)
            acc[mt][nt] = __builtin_amdgcn_mfma_f32_16x16x32_bf16(af[mt], bf4[nt],
                                                                  acc[mt][nt], 0, 0, 0);
    }

    // epilogue: h2 = relu(acc + b2[col]); partial = h2 . W3[col] over 128 cols
    float b2v[4], w3v[4];
#pragma unroll
    for (int nt = 0; nt < 4; ++nt) {
        int col = col0 + wn * 64 + nt * 16 + l15;
        b2v[nt] = b2[col];
        w3v[nt] = W3f[col];
    }
#pragma unroll
    for (int mt = 0; mt < 4; ++mt)
#pragma unroll
    for (int r = 0; r < 4; ++r) {
        int rloc = wm * 64 + mt * 16 + lk * 4 + r;
        float p = 0.f;
#pragma unroll
        for (int nt = 0; nt < 4; ++nt)
            p += fmaxf(acc[mt][nt][r] + b2v[nt], 0.f) * w3v[nt];
        p += __shfl_xor(p, 1); p += __shfl_xor(p, 2);
        p += __shfl_xor(p, 4); p += __shfl_xor(p, 8);
        if (l15 == 0) red[wn][rloc] = p;
    }
    __syncthreads();
    if (tid < 128)
        wpart[blockIdx.x * BM + row0 + tid] = red[0][tid] + red[1][tid];
}

// ---------------------------------------------------------------------------
// Aw[b,x,y] = (y==x) ? 0 : sigmoid(b3 + sum_c wpart[c][row]);  grid 128x256
__global__ void reduce_aw(const float* __restrict__ wpart, const float* __restrict__ b3,
                          float* __restrict__ Aw)
{
    int i = blockIdx.x * 256 + threadIdx.x;     // over 32*16*64
    if (i >= B_ * NH * N_) return;
    int y = i & 63, x = (i >> 6) & 15, b = i >> 10;
    float v = 0.f;
    if (y != x) {
        int j = y - (y > x ? 1 : 0);
        int r = b * M_ + x * 63 + j;
        float s = b3[0] + wpart[r] + wpart[BM + r] + wpart[2 * BM + r] + wpart[3 * BM + r];
        v = 1.f / (1.f + expf(-s));
    }
    Aw[i] = v;
}

// msg_h[b] = A[b] @ Go[b]  ([16,64]@[64,1024], bf16 in/out); grid (32,8), block 128
__global__ __launch_bounds__(128)
void msgh_kernel(const float* __restrict__ Aw, const unsigned short* __restrict__ Go,
                 unsigned short* __restrict__ msgh)
{
    __shared__ float Al[NH * N_];
    __shared__ float Gl[N_][128];
    int b = blockIdx.x, c0 = blockIdx.y * 128, t = threadIdx.x;
    for (int i = t; i < NH * N_; i += 128) Al[i] = Aw[b * NH * N_ + i];
    for (int y = 0; y < N_; ++y) Gl[y][t] = bf2f(Go[((size_t)(b * N_ + y)) * REP + c0 + t]);
    __syncthreads();
    for (int x = 0; x < NH; ++x) {
        float s = 0.f;
#pragma unroll 8
        for (int y = 0; y < N_; ++y) s += Al[x * N_ + y] * Gl[y][t];
        msgh[((size_t)(b * NH + x)) * REP + c0 + t] = f2bf(s);
    }
}

// msg_o[b] = A[b]^T @ Gs[b]  ([64,16]@[16,1024], bf16 in/out); grid (32,8), block 128
__global__ __launch_bounds__(128)
void msgo_kernel(const float* __restrict__ Aw, const unsigned short* __restrict__ Gs,
                 unsigned short* __restrict__ msgo)
{
    __shared__ float Al[NH * N_];
    __shared__ float Gl[NH][128];
    int b = blockIdx.x, c0 = blockIdx.y * 128, t = threadIdx.x;
    for (int i = t; i < NH * N_; i += 128) Al[i] = Aw[b * NH * N_ + i];
    for (int x = 0; x < NH; ++x) Gl[x][t] = bf2f(Gs[((size_t)(b * NH + x)) * REP + c0 + t]);
    __syncthreads();
    for (int y = 0; y < N_; ++y) {
        float s = 0.f;
#pragma unroll
        for (int x = 0; x < NH; ++x) s += Al[x * N_ + y] * Gl[x][t];
        msgo[((size_t)(b * N_ + y)) * REP + c0 + t] = f2bf(s);
    }
}

// ---------------------------------------------------------------------------
__global__ void pair_out(const float* __restrict__ enc, float* __restrict__ out0)
{
    int i = blockIdx.x * 256 + threadIdx.x;     // over 32256*512 float4
    if (i >= BM * 512) return;
    int r = i >> 9, q = i & 511;
    int b = r / M_, m = r % M_;
    int x = m / 63, j = m % 63;
    int y = j + (j >= x ? 1 : 0);
    const float4* e4 = (const float4*)enc;
    float4 v = (q < 256) ? e4[(b * 64 + x) * 256 + q]
                         : e4[(b * 64 + y) * 256 + (q - 256)];
    ((float4*)out0)[i] = v;
}

__global__ void coords_out(const float* __restrict__ coords,
                           float* __restrict__ out1, float* __restrict__ out2)
{
    int r = blockIdx.x * 256 + threadIdx.x;
    if (r >= BM) return;
    int b = r / M_, m = r % M_;
    int x = m / 63, j = m % 63;
    int y = j + (j >= x ? 1 : 0);
    const float4* c4 = (const float4*)coords;
    ((float4*)out1)[r] = c4[b * 64 + x];
    ((float4*)out2)[r] = c4[b * 64 + y];
}

__device__ __forceinline__ float lis_f(float x)
{
    return 8.3f / (1.f + expf(12.f - 10.f * x));
}

__global__ void prior_out(const float* __restrict__ Aw, const int* __restrict__ labels,
                          const float* __restrict__ scores, float* __restrict__ out3)
{
    int i = blockIdx.x * 256 + threadIdx.x;     // over BM*117
    if (i >= BM * NCLS) return;
    int r = i / NCLS, c = i % NCLS;
    int b = r / M_, m = r % M_;
    int x = m / 63, j = m % 63;
    int y = j + (j >= x ? 1 : 0);
    int lab = labels[b * 64 + y];
    float val = 0.f;
    if (c == lab) {
        float sx = scores[b * 64 + x], sy = scores[b * 64 + y];
        val = Aw[(b * NH + x) * N_ + y] * lis_f(sx) * lis_f(sy);
    }
    out3[i] = val;
}

// ---------------------------------------------------------------------------
extern "C" void kernel_launch(void* const* d_in, const int* in_sizes, int n_in,
                              void* d_out, int out_size, void* d_ws, size_t ws_size,
                              hipStream_t stream)
{
    const float* box_features = (const float*)d_in[0];
    const float* box_coords   = (const float*)d_in[1];
    const int*   box_labels   = (const int*)d_in[2];
    const float* box_scores   = (const float*)d_in[3];
    const float* W1  = (const float*)d_in[4];
    const float* b1  = (const float*)d_in[5];
    const float* W2  = (const float*)d_in[6];
    const float* b2  = (const float*)d_in[7];
    const float* W3  = (const float*)d_in[8];
    const float* b3  = (const float*)d_in[9];
    const float* Ws  = (const float*)d_in[10];
    const float* bs  = (const float*)d_in[11];
    const float* Wo  = (const float*)d_in[12];
    const float* bo  = (const float*)d_in[13];
    const float* Wsu = (const float*)d_in[14];
    const float* Wou = (const float*)d_in[15];

    float* wsf  = (float*)d_ws;
    float* encA = wsf;           wsf += (size_t)B_ * N_ * R_;    // fp32 final enc
    float* wpart= wsf;           wsf += (size_t)4 * BM;
    float* Aw   = wsf;           wsf += (size_t)B_ * NH * N_;

    unsigned short* wsu = (unsigned short*)wsf;
    unsigned short* enc0bf = wsu;  wsu += (size_t)B_ * N_ * R_;   // 2M
    unsigned short* encIbf = wsu;  wsu += (size_t)B_ * N_ * R_;   // 2M
    unsigned short* Ubf    = wsu;  wsu += (size_t)B_ * NH * REP;  // 0.5M
    unsigned short* Vbf    = wsu;  wsu += (size_t)B_ * N_ * REP;  // 2M
    unsigned short* Gobf   = wsu;  wsu += (size_t)B_ * N_ * REP;  // 2M
    unsigned short* msghbf = wsu;  wsu += (size_t)B_ * NH * REP;  // 0.5M
    unsigned short* enchbf = wsu;  wsu += (size_t)B_ * NH * R_;   // 0.5M
    unsigned short* Gsbf   = wsu;  wsu += (size_t)B_ * NH * REP;  // 0.5M
    unsigned short* msgobf = wsu;  wsu += (size_t)B_ * N_ * REP;  // 2M
    unsigned short* W1tt = wsu;  wsu += (size_t)1024 * 1024;
    unsigned short* W1tb = wsu;  wsu += (size_t)1024 * 1024;
    unsigned short* W2t  = wsu;  wsu += (size_t)512 * 1024;
    unsigned short* Wot  = wsu;  wsu += (size_t)1024 * 1024;
    unsigned short* Wst  = wsu;  wsu += (size_t)1024 * 1024;
    unsigned short* Wsut = wsu;  wsu += (size_t)1024 * 2048;
    unsigned short* Wout = wsu;  wsu += (size_t)1024 * 2048;

    float* out0 = (float*)d_out;                       // pair [32256, 2048]
    float* out1 = out0 + (size_t)BM * 2048;            // bh   [32,1008,4]
    float* out2 = out1 + (size_t)BM * 4;               // bo   [32,1008,4]
    float* out3 = out2 + (size_t)BM * 4;               // prior[32256, 117]

    // ---- prep: weights bf16-transposed; box_features -> bf16 ----
    cvt_bf<<<1024, 256, 0, stream>>>(box_features, enc0bf);
    transpose_bf<<<dim3(32, 32), 256, 0, stream>>>(W1, W1tt, 1024, 1024);
    transpose_bf<<<dim3(32, 32), 256, 0, stream>>>(W1 + 1024 * 1024, W1tb, 1024, 1024);
    transpose_bf<<<dim3(32, 16), 256, 0, stream>>>(W2, W2t, 1024, 512);
    transpose_bf<<<dim3(32, 32), 256, 0, stream>>>(Wo, Wot, 1024, 1024);
    transpose_bf<<<dim3(32, 32), 256, 0, stream>>>(Ws, Wst, 1024, 1024);
    transpose_bf<<<dim3(64, 32), 256, 0, stream>>>(Wsu, Wsut, 2048, 1024);
    transpose_bf<<<dim3(64, 32), 256, 0, stream>>>(Wou, Wout, 2048, 1024);

    for (int it = 0; it < 2; ++it) {
        const unsigned short* enc = (it == 0) ? enc0bf : encIbf;
        // U = enc[humans] @ W1_top + b1      (row-gather fused)
        gemm_bf<<<dim3(8, 4), 256, 0, stream>>>(enc, nullptr, nullptr, W1tt, b1,
                                                nullptr, Ubf, 1024, 1024, 0, MD_HG);
        // V = enc @ W1_bot
        gemm_bf<<<dim3(8, 16), 256, 0, stream>>>(enc, nullptr, nullptr, W1tb, nullptr,
                                                 nullptr, Vbf, 1024, 1024, 0, MD_DIRECT);
        // fused pair MLP -> wpart; then sigmoid-reduce -> Aw
        pair_bf<<<dim3(4, 252), 256, 0, stream>>>(Ubf, Vbf, W2t, b2, W3, wpart);
        reduce_aw<<<128, 256, 0, stream>>>(wpart, b3, Aw);
        // Go = relu(enc @ Wo + bo)
        gemm_bf<<<dim3(8, 16), 256, 0, stream>>>(enc, nullptr, nullptr, Wot, bo,
                                                 nullptr, Gobf, 1024, 1024, 1, MD_DIRECT);
        msgh_kernel<<<dim3(32, 8), 128, 0, stream>>>(Aw, Gobf, msghbf);
        // ench = concat(enc[humans], msgh) @ Wsu    (K-concat fused)
        gemm_bf<<<dim3(8, 4), 256, 0, stream>>>(enc, msghbf, nullptr, Wsut, nullptr,
                                                nullptr, enchbf, 2048, 1024, 0, MD_CC1);
        // Gs = relu(ench @ Ws + bs)
        gemm_bf<<<dim3(8, 4), 256, 0, stream>>>(enchbf, nullptr, nullptr, Wst, bs,
                                                nullptr, Gsbf, 1024, 1024, 1, MD_DIRECT);
        msgo_kernel<<<dim3(32, 8), 128, 0, stream>>>(Aw, Gsbf, msgobf);
        // encOut = concat(enc_upd, msgo) @ Wou      (K-concat + row-select fused)
        gemm_bf<<<dim3(8, 16), 256, 0, stream>>>(enc, msgobf, enchbf, Wout, nullptr,
                                                 (it == 1) ? encA : nullptr,
                                                 (it == 0) ? encIbf : nullptr,
                                                 2048, 1024, 0, MD_CC2);
    }

    // outputs (final enc = encA fp32; Aw holds last-iter A)
    pair_out<<<64512, 256, 0, stream>>>(encA, out0);
    coords_out<<<126, 256, 0, stream>>>(box_coords, out1, out2);
    prior_out<<<14742, 256, 0, stream>>>(Aw, box_labels, box_scores, out3);
}

// Round 4
// 762.035 us; speedup vs baseline: 4.1379x; 1.3600x over previous
//
#include <hip/hip_runtime.h>

#define B_   32
#define N_   64
#define NH   16
#define R_   1024
#define REP  1024
#define M_   1008           // 16*63
#define BM   (B_ * M_)      // 32256
#define NCLS 117

#define MD_DIRECT 0
#define MD_CC1    2   // k<1024: enc[b*64+x]; k>=1024: msgh[row]      (512 rows)
#define MD_CC2    3   // k<1024: n<16?ench[b*16+n]:enc[row]; k>=1024: msgo[row] (2048 rows)

typedef short bhalf8 __attribute__((ext_vector_type(8)));   // 8 bf16 (4 VGPRs)
typedef float f32x4  __attribute__((ext_vector_type(4)));   // MFMA acc

typedef __attribute__((address_space(3))) void       lds_t;
typedef const __attribute__((address_space(1))) void gbl_t;
__device__ __forceinline__ void gld16(const void* g, void* l)
{
    __builtin_amdgcn_global_load_lds((gbl_t*)g, (lds_t*)l, 16, 0, 0);
}

__device__ __forceinline__ unsigned short f2bf(float f)
{
    union { float f; unsigned int u; } x; x.f = f;
    unsigned int r = x.u + 0x7FFFu + ((x.u >> 16) & 1u);    // round-nearest-even
    return (unsigned short)(r >> 16);
}
__device__ __forceinline__ float bf2f(unsigned short u)
{
    union { unsigned int i; float f; } x; x.i = ((unsigned int)u) << 16; return x.f;
}
__device__ __forceinline__ unsigned int addrelu2(unsigned int a, unsigned int b)
{
    float lo = fmaxf(bf2f((unsigned short)(a & 0xffff)) + bf2f((unsigned short)(b & 0xffff)), 0.f);
    float hi = fmaxf(bf2f((unsigned short)(a >> 16))    + bf2f((unsigned short)(b >> 16)),    0.f);
    return (unsigned int)f2bf(lo) | ((unsigned int)f2bf(hi) << 16);
}

// ---------------------------------------------------------------------------
// One-dispatch weight prep. Segments (32x32 transpose tiles, bf16 out):
//  [0,1024)     W1 bot  -> Wfused rows    0..1023   (V cols)
//  [1024,2048)  Wo      -> Wfused rows 1024..2047   (Go cols)
//  [2048,3072)  W1 top  -> Wfused rows 2048..3071   (U cols)
//  [3072,3584)  W2      -> W2t
//  [3584,4608)  Ws      -> Wst
//  [4608,6656)  Wsu     -> Wsut
//  [6656,8704)  Wou     -> Wout
//  [8704,8716)  biasFull build (0 | bo | b1)
// ---------------------------------------------------------------------------
__device__ __forceinline__ void tr32(const float* in, unsigned short* out,
                                     int K, int N, int local)
{
    __shared__ float t[32][33];
    int kb = K >> 5;
    int k0 = (local % kb) * 32, n0 = (local / kb) * 32;
    int tx = threadIdx.x & 31, ty = threadIdx.x >> 5;
#pragma unroll
    for (int r = 0; r < 4; ++r)
        t[ty + r * 8][tx] = in[(size_t)(k0 + ty + r * 8) * N + n0 + tx];
    __syncthreads();
#pragma unroll
    for (int r = 0; r < 4; ++r)
        out[(size_t)(n0 + ty + r * 8) * K + k0 + tx] = f2bf(t[tx][ty + r * 8]);
}

__global__ __launch_bounds__(256)
void prep_all(const float* __restrict__ W1, const float* __restrict__ W2,
              const float* __restrict__ Wo, const float* __restrict__ Ws,
              const float* __restrict__ Wsu, const float* __restrict__ Wou,
              const float* __restrict__ bo_, const float* __restrict__ b1_,
              unsigned short* __restrict__ Wfused, unsigned short* __restrict__ W2t,
              unsigned short* __restrict__ Wst, unsigned short* __restrict__ Wsut,
              unsigned short* __restrict__ Wout, float* __restrict__ biasFull)
{
    int bx = blockIdx.x;
    if      (bx < 1024) tr32(W1 + 1024 * 1024, Wfused,               1024, 1024, bx);
    else if (bx < 2048) tr32(Wo,               Wfused + 1024 * 1024, 1024, 1024, bx - 1024);
    else if (bx < 3072) tr32(W1,               Wfused + 2048 * 1024, 1024, 1024, bx - 2048);
    else if (bx < 3584) tr32(W2,  W2t,  1024, 512,  bx - 3072);
    else if (bx < 4608) tr32(Ws,  Wst,  1024, 1024, bx - 3584);
    else if (bx < 6656) tr32(Wsu, Wsut, 2048, 1024, bx - 4608);
    else if (bx < 8704) tr32(Wou, Wout, 2048, 1024, bx - 6656);
    else {
        int c = (bx - 8704) * 256 + threadIdx.x;   // 0..3071
        float v = 0.f;
        if (c >= 2048)      v = b1_[c - 2048];
        else if (c >= 1024) v = bo_[c - 1024];
        biasFull[c] = v;
    }
}

// box_features -> bf16 (8 elems/thread)
__global__ void cvt_bf(const float* __restrict__ in, unsigned short* __restrict__ out)
{
    int i = blockIdx.x * 256 + threadIdx.x;     // over 2M/8 = 256K
    float4 a = ((const float4*)in)[2 * i];
    float4 b = ((const float4*)in)[2 * i + 1];
    uint4 o;
    o.x = (unsigned)f2bf(a.x) | ((unsigned)f2bf(a.y) << 16);
    o.y = (unsigned)f2bf(a.z) | ((unsigned)f2bf(a.w) << 16);
    o.z = (unsigned)f2bf(b.x) | ((unsigned)f2bf(b.y) << 16);
    o.w = (unsigned)f2bf(b.z) | ((unsigned)f2bf(b.w) << 16);
    ((uint4*)out)[i] = o;
}

// ---------------------------------------------------------------------------
// Fused U/V/Go GEMM: XX[2048,3072] = enc[2048,1024] @ Wfused^T (+biasFull,
// relu on Go region).  128x128 tile, BK=32, grid (24,16), block 256.
// ---------------------------------------------------------------------------
__global__ __launch_bounds__(256)
void gemm_uvgo(const unsigned short* __restrict__ enc,
               const unsigned short* __restrict__ Wf,
               const float* __restrict__ biasFull, unsigned short* __restrict__ XX)
{
    __shared__ unsigned short As[128 * 32];
    __shared__ unsigned short Bs[128 * 32];
    const int tid  = threadIdx.x;
    const int lane = tid & 63, wave = tid >> 6;
    const int wm = wave & 1, wn = wave >> 1;
    const int l15 = lane & 15, lk = lane >> 4;
    const int row0 = blockIdx.y * 128, col0 = blockIdx.x * 128;
    const int kq = (lane & 3) * 8;

    const unsigned short* pA[2];
    const unsigned short* pB[2];
    unsigned short* AsW[2];
    unsigned short* BsW[2];
#pragma unroll
    for (int i = 0; i < 2; ++i) {
        int tr = wave * 32 + (lane >> 2) + i * 16;
        pA[i]  = enc + (size_t)(row0 + tr) * 1024 + kq;
        pB[i]  = Wf  + (size_t)(col0 + tr) * 1024 + kq;
        AsW[i] = As + wave * 1024 + i * 512 + lane * 8;
        BsW[i] = Bs + wave * 1024 + i * 512 + lane * 8;
    }

    f32x4 acc[4][4];
#pragma unroll
    for (int i = 0; i < 4; ++i)
#pragma unroll
    for (int j = 0; j < 4; ++j) acc[i][j] = (f32x4)0.f;

    for (int k0 = 0; k0 < 1024; k0 += 32) {
        __syncthreads();
        gld16(pA[0] + k0, AsW[0]);
        gld16(pA[1] + k0, AsW[1]);
        gld16(pB[0] + k0, BsW[0]);
        gld16(pB[1] + k0, BsW[1]);
        __syncthreads();
        bhalf8 af[4], bf4[4];
#pragma unroll
        for (int mt = 0; mt < 4; ++mt)
            af[mt] = *(bhalf8*)&As[(wm * 64 + mt * 16 + l15) * 32 + lk * 8];
#pragma unroll
        for (int nt = 0; nt < 4; ++nt)
            bf4[nt] = *(bhalf8*)&Bs[(wn * 64 + nt * 16 + l15) * 32 + lk * 8];
#pragma unroll
        for (int mt = 0; mt < 4; ++mt)
#pragma unroll
        for (int nt = 0; nt < 4; ++nt)
            acc[mt][nt] = __builtin_amdgcn_mfma_f32_16x16x32_bf16(af[mt], bf4[nt],
                                                                  acc[mt][nt], 0, 0, 0);
    }

#pragma unroll
    for (int mt = 0; mt < 4; ++mt)
#pragma unroll
    for (int r = 0; r < 4; ++r) {
        int row = row0 + wm * 64 + mt * 16 + lk * 4 + r;
#pragma unroll
        for (int nt = 0; nt < 4; ++nt) {
            int col = col0 + wn * 64 + nt * 16 + l15;
            float v = acc[mt][nt][r] + biasFull[col];
            if ((col >> 10) == 1) v = fmaxf(v, 0.f);    // Go region
            XX[(size_t)row * 3072 + col] = f2bf(v);
        }
    }
}

// ---------------------------------------------------------------------------
// fused pair MLP: A-rows = relu(U[b,x]+V[b,y]) from XX, GEMM vs W2t,
// epilogue fuses relu(+b2) + W3 dot -> wpart[chunk][row].  grid (4,252).
// ---------------------------------------------------------------------------
__global__ __launch_bounds__(256)
void pair_bf(const unsigned short* __restrict__ XX,
             const unsigned short* __restrict__ W2t, const float* __restrict__ b2,
             const float* __restrict__ W3f, float* __restrict__ wpart)
{
    __shared__ unsigned short As[128 * 32];
    __shared__ unsigned short Bs[128 * 32];
    __shared__ float red[2][128];
    const int tid  = threadIdx.x;
    const int lane = tid & 63, wave = tid >> 6;
    const int wm = wave & 1, wn = wave >> 1;
    const int l15 = lane & 15, lk = lane >> 4;
    const int row0 = blockIdx.y * 128, col0 = blockIdx.x * 128;

    const int srow = tid >> 1, skh = tid & 1;
    int rg = row0 + srow;
    int b  = rg / M_, m = rg % M_;
    int x  = m / 63, jj = m % 63;
    int y  = jj + (jj >= x ? 1 : 0);
    const unsigned short* Up = XX + ((size_t)(b * 64 + x)) * 3072 + 2048 + skh * 16;
    const unsigned short* Vp = XX + ((size_t)(b * 64 + y)) * 3072 + skh * 16;
    unsigned short* AsW = As + srow * 32 + skh * 16;

    const int kq = (lane & 3) * 8;
    const unsigned short* pB[2];
    unsigned short* BsW[2];
#pragma unroll
    for (int i = 0; i < 2; ++i) {
        int tr = wave * 32 + (lane >> 2) + i * 16;
        pB[i]  = W2t + (size_t)(col0 + tr) * REP + kq;
        BsW[i] = Bs + wave * 1024 + i * 512 + lane * 8;
    }

    f32x4 acc[4][4];
#pragma unroll
    for (int i = 0; i < 4; ++i)
#pragma unroll
    for (int j = 0; j < 4; ++j) acc[i][j] = (f32x4)0.f;

    for (int k0 = 0; k0 < REP; k0 += 32) {
        uint4 uu0 = *(const uint4*)(Up + k0);
        uint4 uu1 = *(const uint4*)(Up + k0 + 8);
        uint4 vv0 = *(const uint4*)(Vp + k0);
        uint4 vv1 = *(const uint4*)(Vp + k0 + 8);
        uint4 h0, h1;
        h0.x = addrelu2(uu0.x, vv0.x); h0.y = addrelu2(uu0.y, vv0.y);
        h0.z = addrelu2(uu0.z, vv0.z); h0.w = addrelu2(uu0.w, vv0.w);
        h1.x = addrelu2(uu1.x, vv1.x); h1.y = addrelu2(uu1.y, vv1.y);
        h1.z = addrelu2(uu1.z, vv1.z); h1.w = addrelu2(uu1.w, vv1.w);
        __syncthreads();
        *(uint4*)(AsW)     = h0;
        *(uint4*)(AsW + 8) = h1;
        gld16(pB[0] + k0, BsW[0]);
        gld16(pB[1] + k0, BsW[1]);
        __syncthreads();
        bhalf8 af[4], bf4[4];
#pragma unroll
        for (int mt = 0; mt < 4; ++mt)
            af[mt] = *(bhalf8*)&As[(wm * 64 + mt * 16 + l15) * 32 + lk * 8];
#pragma unroll
        for (int nt = 0; nt < 4; ++nt)
            bf4[nt] = *(bhalf8*)&Bs[(wn * 64 + nt * 16 + l15) * 32 + lk * 8];
#pragma unroll
        for (int mt = 0; mt < 4; ++mt)
#pragma unroll
        for (int nt = 0; nt < 4; ++nt)
            acc[mt][nt] = __builtin_amdgcn_mfma_f32_16x16x32_bf16(af[mt], bf4[nt],
                                                                  acc[mt][nt], 0, 0, 0);
    }

    float b2v[4], w3v[4];
#pragma unroll
    for (int nt = 0; nt < 4; ++nt) {
        int col = col0 + wn * 64 + nt * 16 + l15;
        b2v[nt] = b2[col];
        w3v[nt] = W3f[col];
    }
#pragma unroll
    for (int mt = 0; mt < 4; ++mt)
#pragma unroll
    for (int r = 0; r < 4; ++r) {
        int rloc = wm * 64 + mt * 16 + lk * 4 + r;
        float p = 0.f;
#pragma unroll
        for (int nt = 0; nt < 4; ++nt)
            p += fmaxf(acc[mt][nt][r] + b2v[nt], 0.f) * w3v[nt];
        p += __shfl_xor(p, 1); p += __shfl_xor(p, 2);
        p += __shfl_xor(p, 4); p += __shfl_xor(p, 8);
        if (l15 == 0) red[wn][rloc] = p;
    }
    __syncthreads();
    if (tid < 128)
        wpart[blockIdx.x * BM + row0 + tid] = red[0][tid] + red[1][tid];
}

// ---------------------------------------------------------------------------
// compute A-row for image b into Al[1024] (x-major) from wpart; sigmoid fused.
__device__ __forceinline__ void compute_A(const float* __restrict__ wpart, float b3v,
                                          int b, float* Al, int t)
{
    for (int i = t; i < NH * N_; i += 128) {
        int y = i & 63, x = i >> 6;
        float v = 0.f;
        if (y != x) {
            int j = y - (y > x ? 1 : 0);
            int r = b * M_ + x * 63 + j;
            float s = b3v + wpart[r] + wpart[BM + r] + wpart[2 * BM + r] + wpart[3 * BM + r];
            v = 1.f / (1.f + expf(-s));
        }
        Al[i] = v;
    }
}

// msg_h[b] = A[b] @ Go[b] (Go = XX[:,1024:2048]); also writes Aw (blockIdx.y==0)
__global__ __launch_bounds__(128)
void msgh_kernel(const float* __restrict__ wpart, const float* __restrict__ b3,
                 const unsigned short* __restrict__ XX,
                 unsigned short* __restrict__ msgh, float* __restrict__ Aw)
{
    __shared__ float Al[NH * N_];
    __shared__ float Gl[N_][128];
    int b = blockIdx.x, c0 = blockIdx.y * 128, t = threadIdx.x;
    compute_A(wpart, b3[0], b, Al, t);
    for (int y = 0; y < N_; ++y)
        Gl[y][t] = bf2f(XX[((size_t)(b * 64 + y)) * 3072 + 1024 + c0 + t]);
    __syncthreads();
    if (blockIdx.y == 0)
        for (int i = t; i < NH * N_; i += 128) Aw[b * NH * N_ + i] = Al[i];
    for (int x = 0; x < NH; ++x) {
        float s = 0.f;
#pragma unroll 8
        for (int y = 0; y < N_; ++y) s += Al[x * N_ + y] * Gl[y][t];
        msgh[((size_t)(b * NH + x)) * REP + c0 + t] = f2bf(s);
    }
}

// msg_o[b] = A[b]^T @ Gs[b]
__global__ __launch_bounds__(128)
void msgo_kernel(const float* __restrict__ wpart, const float* __restrict__ b3,
                 const unsigned short* __restrict__ Gs, unsigned short* __restrict__ msgo)
{
    __shared__ float Al[NH * N_];
    __shared__ float Gl[NH][128];
    int b = blockIdx.x, c0 = blockIdx.y * 128, t = threadIdx.x;
    compute_A(wpart, b3[0], b, Al, t);
    for (int x = 0; x < NH; ++x)
        Gl[x][t] = bf2f(Gs[((size_t)(b * NH + x)) * REP + c0 + t]);
    __syncthreads();
    for (int y = 0; y < N_; ++y) {
        float s = 0.f;
#pragma unroll
        for (int x = 0; x < NH; ++x) s += Al[x * N_ + y] * Gl[x][t];
        msgo[((size_t)(b * N_ + y)) * REP + c0 + t] = f2bf(s);
    }
}

// ---------------------------------------------------------------------------
// 64x64-tile bf16 MFMA GEMM for small shapes; BK=32, block 256 (4 waves 32x32).
// grid (Nc/64, M/64).  A rows mapped per mode.
// ---------------------------------------------------------------------------
__global__ __launch_bounds__(256)
void gemm_small(const unsigned short* __restrict__ A1, const unsigned short* __restrict__ A2,
                const unsigned short* __restrict__ A3, const unsigned short* __restrict__ Bt,
                const float* __restrict__ bias, float* __restrict__ Cf,
                unsigned short* __restrict__ Cb, int K, int Nc, int doRelu, int mode)
{
    __shared__ unsigned short As[64 * 32];
    __shared__ unsigned short Bs[64 * 32];
    const int tid  = threadIdx.x;
    const int lane = tid & 63, wave = tid >> 6;
    const int wr = wave & 1, wc = wave >> 1;
    const int l15 = lane & 15, lk = lane >> 4;
    const int row0 = blockIdx.y * 64, col0 = blockIdx.x * 64;
    const int kq = (lane & 3) * 8;

    int tr = wave * 16 + (lane >> 2);   // 0..63
    int rr = row0 + tr;
    const unsigned short* p1;
    const unsigned short* p2 = nullptr;
    if (mode == MD_DIRECT) {
        p1 = A1 + (size_t)rr * K;
    } else if (mode == MD_CC1) {
        int b = rr >> 4, x = rr & 15;
        p1 = A1 + (size_t)(b * 64 + x) * 1024;
        p2 = A2 + (size_t)rr * 1024 - 1024;
    } else {
        int b = rr >> 6, n = rr & 63;
        p1 = (n < 16) ? A3 + (size_t)(b * 16 + n) * 1024
                      : A1 + (size_t)rr * 1024;
        p2 = A2 + (size_t)rr * 1024 - 1024;
    }
    const unsigned short* pA1 = p1 + kq;
    const unsigned short* pA2 = p2 ? p2 + kq : nullptr;
    const unsigned short* pB  = Bt + (size_t)(col0 + tr) * K + kq;
    unsigned short* AsW = As + wave * 512 + lane * 8;
    unsigned short* BsW = Bs + wave * 512 + lane * 8;
    const int kSw = (mode != MD_DIRECT) ? 1024 : K;

    f32x4 acc[2][2];
#pragma unroll
    for (int i = 0; i < 2; ++i)
#pragma unroll
    for (int j = 0; j < 2; ++j) acc[i][j] = (f32x4)0.f;

    for (int k0 = 0; k0 < K; k0 += 32) {
        const unsigned short* a = (k0 < kSw) ? pA1 : pA2;
        __syncthreads();
        gld16(a + k0,  AsW);
        gld16(pB + k0, BsW);
        __syncthreads();
        bhalf8 af[2], bf4[2];
#pragma unroll
        for (int mt = 0; mt < 2; ++mt)
            af[mt] = *(bhalf8*)&As[(wr * 32 + mt * 16 + l15) * 32 + lk * 8];
#pragma unroll
        for (int nt = 0; nt < 2; ++nt)
            bf4[nt] = *(bhalf8*)&Bs[(wc * 32 + nt * 16 + l15) * 32 + lk * 8];
#pragma unroll
        for (int mt = 0; mt < 2; ++mt)
#pragma unroll
        for (int nt = 0; nt < 2; ++nt)
            acc[mt][nt] = __builtin_amdgcn_mfma_f32_16x16x32_bf16(af[mt], bf4[nt],
                                                                  acc[mt][nt], 0, 0, 0);
    }

#pragma unroll
    for (int mt = 0; mt < 2; ++mt)
#pragma unroll
    for (int r = 0; r < 4; ++r) {
        int row = row0 + wr * 32 + mt * 16 + lk * 4 + r;
#pragma unroll
        for (int nt = 0; nt < 2; ++nt) {
            int col = col0 + wc * 32 + nt * 16 + l15;
            float v = acc[mt][nt][r];
            if (bias) v += bias[col];
            if (doRelu) v = fmaxf(v, 0.f);
            if (Cf) Cf[(size_t)row * Nc + col] = v;
            if (Cb) Cb[(size_t)row * Nc + col] = f2bf(v);
        }
    }
}

// ---------------------------------------------------------------------------
__global__ void pair_out(const float* __restrict__ enc, float* __restrict__ out0)
{
    int i = blockIdx.x * 256 + threadIdx.x;     // over 32256*512 float4
    if (i >= BM * 512) return;
    int r = i >> 9, q = i & 511;
    int b = r / M_, m = r % M_;
    int x = m / 63, j = m % 63;
    int y = j + (j >= x ? 1 : 0);
    const float4* e4 = (const float4*)enc;
    float4 v = (q < 256) ? e4[(b * 64 + x) * 256 + q]
                         : e4[(b * 64 + y) * 256 + (q - 256)];
    ((float4*)out0)[i] = v;
}

__global__ void coords_out(const float* __restrict__ coords,
                           float* __restrict__ out1, float* __restrict__ out2)
{
    int r = blockIdx.x * 256 + threadIdx.x;
    if (r >= BM) return;
    int b = r / M_, m = r % M_;
    int x = m / 63, j = m % 63;
    int y = j + (j >= x ? 1 : 0);
    const float4* c4 = (const float4*)coords;
    ((float4*)out1)[r] = c4[b * 64 + x];
    ((float4*)out2)[r] = c4[b * 64 + y];
}

__device__ __forceinline__ float lis_f(float x)
{
    return 8.3f / (1.f + expf(12.f - 10.f * x));
}

__global__ void prior_out(const float* __restrict__ Aw, const int* __restrict__ labels,
                          const float* __restrict__ scores, float* __restrict__ out3)
{
    int i = blockIdx.x * 256 + threadIdx.x;     // over BM*117
    if (i >= BM * NCLS) return;
    int r = i / NCLS, c = i % NCLS;
    int b = r / M_, m = r % M_;
    int x = m / 63, j = m % 63;
    int y = j + (j >= x ? 1 : 0);
    int lab = labels[b * 64 + y];
    float val = 0.f;
    if (c == lab) {
        float sx = scores[b * 64 + x], sy = scores[b * 64 + y];
        val = Aw[(b * NH + x) * N_ + y] * lis_f(sx) * lis_f(sy);
    }
    out3[i] = val;
}

// ---------------------------------------------------------------------------
extern "C" void kernel_launch(void* const* d_in, const int* in_sizes, int n_in,
                              void* d_out, int out_size, void* d_ws, size_t ws_size,
                              hipStream_t stream)
{
    const float* box_features = (const float*)d_in[0];
    const float* box_coords   = (const float*)d_in[1];
    const int*   box_labels   = (const int*)d_in[2];
    const float* box_scores   = (const float*)d_in[3];
    const float* W1  = (const float*)d_in[4];
    const float* b1  = (const float*)d_in[5];
    const float* W2  = (const float*)d_in[6];
    const float* b2  = (const float*)d_in[7];
    const float* W3  = (const float*)d_in[8];
    const float* b3  = (const float*)d_in[9];
    const float* Ws  = (const float*)d_in[10];
    const float* bs  = (const float*)d_in[11];
    const float* Wo  = (const float*)d_in[12];
    const float* bo  = (const float*)d_in[13];
    const float* Wsu = (const float*)d_in[14];
    const float* Wou = (const float*)d_in[15];

    float* wsf  = (float*)d_ws;
    float* encA = wsf;           wsf += (size_t)B_ * N_ * R_;    // fp32 final enc
    float* wpart= wsf;           wsf += (size_t)4 * BM;
    float* Aw   = wsf;           wsf += (size_t)B_ * NH * N_;
    float* biasFull = wsf;       wsf += 3072;

    unsigned short* wsu = (unsigned short*)wsf;
    unsigned short* enc0bf = wsu;  wsu += (size_t)B_ * N_ * R_;     // 2M
    unsigned short* encIbf = wsu;  wsu += (size_t)B_ * N_ * R_;     // 2M
    unsigned short* XX     = wsu;  wsu += (size_t)B_ * N_ * 3072;   // 6.3M
    unsigned short* msghbf = wsu;  wsu += (size_t)B_ * NH * REP;    // 0.5M
    unsigned short* enchbf = wsu;  wsu += (size_t)B_ * NH * R_;     // 0.5M
    unsigned short* Gsbf   = wsu;  wsu += (size_t)B_ * NH * REP;    // 0.5M
    unsigned short* msgobf = wsu;  wsu += (size_t)B_ * N_ * REP;    // 2M
    unsigned short* Wfused = wsu;  wsu += (size_t)3072 * 1024;
    unsigned short* W2t    = wsu;  wsu += (size_t)512 * 1024;
    unsigned short* Wst    = wsu;  wsu += (size_t)1024 * 1024;
    unsigned short* Wsut   = wsu;  wsu += (size_t)1024 * 2048;
    unsigned short* Wout   = wsu;  wsu += (size_t)1024 * 2048;

    float* out0 = (float*)d_out;                       // pair [32256, 2048]
    float* out1 = out0 + (size_t)BM * 2048;            // bh   [32,1008,4]
    float* out2 = out1 + (size_t)BM * 4;               // bo   [32,1008,4]
    float* out3 = out2 + (size_t)BM * 4;               // prior[32256, 117]

    // ---- prep (2 dispatches) ----
    prep_all<<<8716, 256, 0, stream>>>(W1, W2, Wo, Ws, Wsu, Wou, bo, b1,
                                       Wfused, W2t, Wst, Wsut, Wout, biasFull);
    cvt_bf<<<1024, 256, 0, stream>>>(box_features, enc0bf);

    for (int it = 0; it < 2; ++it) {
        const unsigned short* enc = (it == 0) ? enc0bf : encIbf;
        // XX = enc @ [W1bot | Wo | W1top]  (V | Go | Ufull)
        gemm_uvgo<<<dim3(24, 16), 256, 0, stream>>>(enc, Wfused, biasFull, XX);
        // fused pair MLP -> wpart
        pair_bf<<<dim3(4, 252), 256, 0, stream>>>(XX, W2t, b2, W3, wpart);
        // msgh = A @ Go  (A recomputed from wpart; Aw written for prior_out)
        msgh_kernel<<<dim3(32, 8), 128, 0, stream>>>(wpart, b3, XX, msghbf, Aw);
        // ench = concat(enc[humans], msgh) @ Wsu
        gemm_small<<<dim3(16, 8), 256, 0, stream>>>(enc, msghbf, nullptr, Wsut, nullptr,
                                                    nullptr, enchbf, 2048, 1024, 0, MD_CC1);
        // Gs = relu(ench @ Ws + bs)
        gemm_small<<<dim3(16, 8), 256, 0, stream>>>(enchbf, nullptr, nullptr, Wst, bs,
                                                    nullptr, Gsbf, 1024, 1024, 1, MD_DIRECT);
        // msgo = A^T @ Gs
        msgo_kernel<<<dim3(32, 8), 128, 0, stream>>>(wpart, b3, Gsbf, msgobf);
        // encOut = concat(enc_upd, msgo) @ Wou
        gemm_small<<<dim3(16, 32), 256, 0, stream>>>(enc, msgobf, enchbf, Wout, nullptr,
                                                     (it == 1) ? encA : nullptr,
                                                     (it == 0) ? encIbf : nullptr,
                                                     1024 * 2, 1024, 0, MD_CC2);
    }

    // outputs
    pair_out<<<64512, 256, 0, stream>>>(encA, out0);
    coords_out<<<126, 256, 0, stream>>>(box_coords, out1, out2);
    prior_out<<<14742, 256, 0, stream>>>(Aw, box_labels, box_scores, out3);
}